// Round 1
// baseline (53445.911 us; speedup 1.0000x reference)
//
#include <hip/hip_runtime.h>
#include <cstdint>
#include <cfloat>
#include <cmath>

// ---------------------------------------------------------------------------
// MossTTS local transformer decode, B=256, H=1024, L=4, HQ=16, HKV=8, D=64,
// I=4096, V=1027, C=16.
//
// KEY INSIGHT: seq_len == 1 -> softmax over one key == 1.0 -> attention output
// o == repeat(v). w_q / w_k / q_norm / k_norm are dead. Layer is:
//   x = rms(h)*wi ; v = x@wv ; h += gather(v)@wo ;
//   x2 = rms(h)*wp ; h += (silu(x2@wg)*(x2@wu))@wd
//
// Sampling must reproduce JAX threefry bit-exactly. PARTITIONABLE=1 uses the
// modern JAX default (split: key_i = tf(key,0,i); bits = o0^o1 of
// tf(key_i,0,idx)). Set to 0 for legacy (concat-halves) semantics if round-0
// tokens mismatch wholesale.
// ---------------------------------------------------------------------------

#define PARTITIONABLE 1

namespace {
constexpr int B = 256, H = 1024, L = 4, HKV = 8, D = 64;
constexpr int I = 4096, V = 1027, C = 16;
constexpr int KV = HKV * D;  // 512
}

// ------------------------------ threefry2x32 -------------------------------
__device__ __forceinline__ void tf2x32(uint32_t k0, uint32_t k1,
                                       uint32_t x0, uint32_t x1,
                                       uint32_t& o0, uint32_t& o1) {
  uint32_t k2 = k0 ^ k1 ^ 0x1BD11BDAu;
  x0 += k0; x1 += k1;
#define TFR(r) { x0 += x1; x1 = (x1 << r) | (x1 >> (32 - r)); x1 ^= x0; }
  TFR(13) TFR(15) TFR(26) TFR(6)
  x0 += k1; x1 += k2 + 1u;
  TFR(17) TFR(29) TFR(16) TFR(24)
  x0 += k2; x1 += k0 + 2u;
  TFR(13) TFR(15) TFR(26) TFR(6)
  x0 += k0; x1 += k1 + 3u;
  TFR(17) TFR(29) TFR(16) TFR(24)
  x0 += k1; x1 += k2 + 4u;
  TFR(13) TFR(15) TFR(26) TFR(6)
  x0 += k2; x1 += k0 + 5u;
#undef TFR
  o0 = x0; o1 = x1;
}

__device__ __forceinline__ float gumbel_for(uint32_t k0, uint32_t k1,
                                            uint32_t idx) {
  uint32_t o0, o1, bits;
#if PARTITIONABLE
  tf2x32(k0, k1, 0u, idx, o0, o1);
  bits = o0 ^ o1;
#else
  const uint32_t half = (uint32_t)(B * V) / 2u;  // 131456
  if (idx < half) { tf2x32(k0, k1, idx, idx + half, o0, o1); bits = o0; }
  else           { tf2x32(k0, k1, idx - half, idx, o0, o1); bits = o1; }
#endif
  // jax.random.uniform: f in [0,1) from high 23 bits; u = max(tiny, f+tiny)
  float f = __uint_as_float((bits >> 9) | 0x3f800000u) - 1.0f;
  float u = fmaxf(FLT_MIN, f + FLT_MIN);
  return -logf(-logf(u));
}

// ------------------------------ simple kernels ------------------------------
__global__ __launch_bounds__(256) void copy_k(float* __restrict__ dst,
                                              const float* __restrict__ src,
                                              int n) {
  int i = blockIdx.x * 256 + threadIdx.x;
  if (i < n) dst[i] = src[i];
}

// x = h * (1/sqrt(mean(h^2)+eps)) * w   (one block per row, H=1024)
__global__ __launch_bounds__(256) void rmsnorm_k(const float* __restrict__ in,
                                                 const float* __restrict__ w,
                                                 float* __restrict__ out) {
  int b = blockIdx.x, tid = threadIdx.x;
  const float* row = in + (size_t)b * H;
  float v0[4]; float s = 0.f;
#pragma unroll
  for (int i = 0; i < 4; ++i) { v0[i] = row[tid + 256 * i]; s += v0[i] * v0[i]; }
  for (int off = 32; off > 0; off >>= 1) s += __shfl_down(s, off, 64);
  __shared__ float red[4];
  int wave = tid >> 6, lane = tid & 63;
  if (lane == 0) red[wave] = s;
  __syncthreads();
  float tot = red[0] + red[1] + red[2] + red[3];
  float r = 1.0f / sqrtf(tot * (1.0f / 1024.0f) + 1e-6f);
#pragma unroll
  for (int i = 0; i < 4; ++i) {
    int j = tid + 256 * i;
    out[(size_t)b * H + j] = v0[i] * r * w[j];
  }
}

// h[b,:] = table[tok[b],:]
__global__ __launch_bounds__(256) void embed_k(float* __restrict__ h,
                                               const float* __restrict__ table,
                                               const int* __restrict__ toks) {
  int b = blockIdx.x;
  int t = toks[b];
  const float* src = table + (size_t)t * H;
  for (int j = threadIdx.x; j < H; j += 256) h[(size_t)b * H + j] = src[j];
}

// repetition penalty (reads all history values before writing: .set semantics)
__global__ __launch_bounds__(256) void reppen_k(float* __restrict__ logits,
                                                const int* __restrict__ gh,
                                                const int* __restrict__ gen_step_p,
                                                int step) {
  int b = threadIdx.x;
  int gs = *gen_step_p;
  int cnt = gs < 50 ? gs : 50;
  int start = gs - cnt;
  int t[50]; float vals[50];
  for (int k = 0; k < cnt; ++k)
    t[k] = gh[(size_t)b * 200 * C + (size_t)(start + k) * C + step];
  for (int k = 0; k < cnt; ++k) vals[k] = logits[(size_t)b * V + t[k]];
  for (int k = 0; k < cnt; ++k) {
    float c = vals[k];
    logits[(size_t)b * V + t[k]] = (c < 0.f) ? c * 1.1f : c / 1.1f;
  }
}

// ------------------------------ GEMM -----------------------------------
// C[M,N] (+)= A[M,K(logical)] * B ; A column k maps to ((k>>7)<<6)|(k&63)
// when GATHER (the repeat-KV gather). B is [K,N] (BT=false) or [N,K] (BT=true).
template <int BM, int BN, int BK, int RM, int RN, bool GATHER, bool ACCUM, bool BT>
__global__ __launch_bounds__(256) void gemm_k(const float* __restrict__ A, int lda,
                                              const float* __restrict__ Bm,
                                              float* __restrict__ Cm,
                                              int M, int N, int K) {
  __shared__ float As[BK][BM + 1];
  __shared__ float Bs[BK][BN + 1];
  const int tid = threadIdx.x;
  const int bm = blockIdx.y * BM;
  const int bn = blockIdx.x * BN;
  const int tx = tid % (BN / RN);
  const int ty = tid / (BN / RN);
  float acc[RM][RN] = {};
  for (int k0 = 0; k0 < K; k0 += BK) {
    for (int idx = tid; idx < BM * BK; idx += 256) {
      int r = idx / BK, c = idx % BK;
      int kk = k0 + c;
      int col = GATHER ? (((kk >> 7) << 6) | (kk & 63)) : kk;
      As[c][r] = A[(size_t)(bm + r) * lda + col];
    }
    if (!BT) {
      for (int idx = tid; idx < BK * BN; idx += 256) {
        int r = idx / BN, c = idx % BN;
        int n = bn + c;
        Bs[r][c] = (n < N) ? Bm[(size_t)(k0 + r) * N + n] : 0.f;
      }
    } else {
      for (int idx = tid; idx < BK * BN; idx += 256) {
        int nn = idx / BK, c = idx % BK;
        int n = bn + nn;
        Bs[c][nn] = (n < N) ? Bm[(size_t)n * K + k0 + c] : 0.f;
      }
    }
    __syncthreads();
#pragma unroll
    for (int kk = 0; kk < BK; ++kk) {
      float a[RM], b[RN];
#pragma unroll
      for (int i = 0; i < RM; ++i) a[i] = As[kk][ty * RM + i];
#pragma unroll
      for (int j = 0; j < RN; ++j) b[j] = Bs[kk][tx * RN + j];
#pragma unroll
      for (int i = 0; i < RM; ++i)
#pragma unroll
        for (int j = 0; j < RN; ++j) acc[i][j] = fmaf(a[i], b[j], acc[i][j]);
    }
    __syncthreads();
  }
#pragma unroll
  for (int i = 0; i < RM; ++i)
#pragma unroll
    for (int j = 0; j < RN; ++j) {
      int r = bm + ty * RM + i, c = bn + tx * RN + j;
      if (c < N) {
        if (ACCUM) Cm[(size_t)r * N + c] += acc[i][j];
        else Cm[(size_t)r * N + c] = acc[i][j];
      }
    }
}

// fused gate/up + silu: m = silu(x@Wg) * (x@Wu)
template <int BM, int BN, int BK, int RM, int RN>
__global__ __launch_bounds__(256) void gemm_gu_k(const float* __restrict__ A,
                                                 const float* __restrict__ Bg,
                                                 const float* __restrict__ Bu,
                                                 float* __restrict__ Mo,
                                                 int M, int N, int K) {
  __shared__ float As[BK][BM + 1];
  __shared__ float Gs[BK][BN + 1];
  __shared__ float Us[BK][BN + 1];
  const int tid = threadIdx.x;
  const int bm = blockIdx.y * BM;
  const int bn = blockIdx.x * BN;
  const int tx = tid % (BN / RN);
  const int ty = tid / (BN / RN);
  float ag[RM][RN] = {}, au[RM][RN] = {};
  for (int k0 = 0; k0 < K; k0 += BK) {
    for (int idx = tid; idx < BM * BK; idx += 256) {
      int r = idx / BK, c = idx % BK;
      As[c][r] = A[(size_t)(bm + r) * K + k0 + c];
    }
    for (int idx = tid; idx < BK * BN; idx += 256) {
      int r = idx / BN, c = idx % BN;
      Gs[r][c] = Bg[(size_t)(k0 + r) * N + bn + c];
      Us[r][c] = Bu[(size_t)(k0 + r) * N + bn + c];
    }
    __syncthreads();
#pragma unroll
    for (int kk = 0; kk < BK; ++kk) {
      float a[RM], g[RN], u[RN];
#pragma unroll
      for (int i = 0; i < RM; ++i) a[i] = As[kk][ty * RM + i];
#pragma unroll
      for (int j = 0; j < RN; ++j) { g[j] = Gs[kk][tx * RN + j]; u[j] = Us[kk][tx * RN + j]; }
#pragma unroll
      for (int i = 0; i < RM; ++i)
#pragma unroll
        for (int j = 0; j < RN; ++j) {
          ag[i][j] = fmaf(a[i], g[j], ag[i][j]);
          au[i][j] = fmaf(a[i], u[j], au[i][j]);
        }
    }
    __syncthreads();
  }
#pragma unroll
  for (int i = 0; i < RM; ++i)
#pragma unroll
    for (int j = 0; j < RN; ++j) {
      int r = bm + ty * RM + i, c = bn + tx * RN + j;
      float g = ag[i][j];
      float sg = 1.0f / (1.0f + expf(-g));
      Mo[(size_t)r * N + c] = g * sg * au[i][j];
    }
}

// ------------------------------ sampler ------------------------------------
// One block per batch row. temp -> top-k(30) -> top-p(0.6) -> gumbel argmax.
__global__ __launch_bounds__(256) void sample_k(const float* __restrict__ logits,
                                                int step,
                                                int* __restrict__ toks,
                                                int* __restrict__ out) {
  constexpr int TOPK = 30;
  constexpr int KMAX = 64;
  const int b = blockIdx.x, tid = threadIdx.x;
  __shared__ float sl[V];
  __shared__ float rv[256]; __shared__ int ri[256];
  __shared__ float topv[TOPK]; __shared__ int topi[TOPK];
  __shared__ float kv[KMAX]; __shared__ int ki[KMAX]; __shared__ int keepf[KMAX];
  __shared__ uint32_t skey[2];
  __shared__ int scnt, sn;

  // per-step key derived from split(key(1234), 16)
  if (tid == 0) {
#if PARTITIONABLE
    uint32_t o0, o1;
    tf2x32(0u, 1234u, 0u, (uint32_t)step, o0, o1);
    skey[0] = o0; skey[1] = o1;
#else
    uint32_t w[2];
    for (int q = 0; q < 2; ++q) {
      uint32_t t = (uint32_t)(2 * step + q), a, c;
      if (t < 16u) { tf2x32(0u, 1234u, t, t + 16u, a, c); w[q] = a; }
      else         { tf2x32(0u, 1234u, t - 16u, t, a, c); w[q] = c; }
    }
    skey[0] = w[0]; skey[1] = w[1];
#endif
    scnt = 0;
  }
  for (int v = tid; v < V; v += 256) sl[v] = logits[(size_t)b * V + v] / 0.8f;
  __syncthreads();

  // iterative top-30 (argmax w/ lowest-index tiebreak, zap, repeat)
  for (int it = 0; it < TOPK; ++it) {
    float bv = -INFINITY; int bi = 0x7fffffff;
    for (int v = tid; v < V; v += 256) {
      float x = sl[v];
      if (x > bv) { bv = x; bi = v; }
    }
    rv[tid] = bv; ri[tid] = bi;
    __syncthreads();
    for (int s = 128; s > 0; s >>= 1) {
      if (tid < s) {
        float ov = rv[tid + s]; int oi = ri[tid + s];
        if (ov > rv[tid] || (ov == rv[tid] && oi < ri[tid])) { rv[tid] = ov; ri[tid] = oi; }
      }
      __syncthreads();
    }
    if (tid == 0) { topv[it] = rv[0]; topi[it] = ri[0]; sl[ri[0]] = -INFINITY; }
    __syncthreads();
  }
  // restore zapped values, collect kept set (l >= thr)
  if (tid < TOPK) sl[topi[tid]] = topv[tid];
  __syncthreads();
  const float thr = topv[TOPK - 1];
  for (int v = tid; v < V; v += 256) {
    if (sl[v] >= thr) {
      int p = atomicAdd(&scnt, 1);
      if (p < KMAX) { kv[p] = sl[v]; ki[p] = v; }
    }
  }
  __syncthreads();

  if (tid == 0) {
    int n = scnt < KMAX ? scnt : KMAX;
    // stable ascending sort by (value, index) == jnp stable argsort
    for (int a = 1; a < n; ++a) {
      float cv = kv[a]; int ci = ki[a];
      int p = a - 1;
      while (p >= 0 && (kv[p] > cv || (kv[p] == cv && ki[p] > ci))) {
        kv[p + 1] = kv[p]; ki[p + 1] = ki[p]; --p;
      }
      kv[p + 1] = cv; ki[p + 1] = ci;
    }
    // softmax over kept (others are exactly 0), sequential cumsum, drop cp<=0.4
    float mx = kv[n - 1];
    float denom = 0.f;
    for (int j = 0; j < n; ++j) denom += expf(kv[j] - mx);
    float c = 0.f;
    for (int j = 0; j < n; ++j) {
      float p = expf(kv[j] - mx) / denom;
      c += p;
      keepf[j] = ((double)c > 0.4) ? 1 : 0;
    }
    sn = n;
  }
  __syncthreads();

  // gumbel argmax over survivors
  int n = sn;
  rv[tid] = -INFINITY; ri[tid] = 0x7fffffff;
  if (tid < n && keepf[tid]) {
    uint32_t idx = (uint32_t)b * (uint32_t)V + (uint32_t)ki[tid];
    float g = gumbel_for(skey[0], skey[1], idx);
    rv[tid] = kv[tid] + g;
    ri[tid] = ki[tid];
  }
  __syncthreads();
  for (int s = 128; s > 0; s >>= 1) {
    if (tid < s) {
      float ov = rv[tid + s]; int oi = ri[tid + s];
      if (ov > rv[tid] || (ov == rv[tid] && oi < ri[tid])) { rv[tid] = ov; ri[tid] = oi; }
    }
    __syncthreads();
  }
  if (tid == 0) {
    int tok = ri[0];
    toks[b] = tok;
    out[(size_t)b * C + step] = tok;
  }
}

// ------------------------------ launch -------------------------------------
extern "C" void kernel_launch(void* const* d_in, const int* in_sizes, int n_in,
                              void* d_out, int out_size, void* d_ws, size_t ws_size,
                              hipStream_t stream) {
  const float* backbone  = (const float*)d_in[0];
  const int*   gh        = (const int*)d_in[1];
  const int*   gen_step  = (const int*)d_in[2];
  const float* embed     = (const float*)d_in[3];
  const float* lm        = (const float*)d_in[4];
  const float* w_in_norm = (const float*)d_in[5];
  // d_in[6]=w_q, d_in[7]=w_k, d_in[9]=q_norm, d_in[10]=k_norm -> DEAD (seq_len==1)
  const float* w_v       = (const float*)d_in[8];
  const float* w_o       = (const float*)d_in[11];
  const float* w_post    = (const float*)d_in[12];
  const float* w_gate    = (const float*)d_in[13];
  const float* w_up      = (const float*)d_in[14];
  const float* w_down    = (const float*)d_in[15];
  const float* fnorm     = (const float*)d_in[16];
  int* out = (int*)d_out;

  float* ws = (float*)d_ws;
  float* h      = ws;                 // 256*1024
  float* x      = ws + 262144;        // 256*1024
  float* v      = ws + 524288;        // 256*512
  float* m      = ws + 655360;        // 256*4096
  float* logits = ws + 1703936;       // 256*1027
  int*   toks   = (int*)(ws + 1966848);

  copy_k<<<dim3((B * H + 255) / 256), dim3(256), 0, stream>>>(h, backbone, B * H);

  for (int i = 0; i < C; ++i) {
    for (int l = 0; l < L; ++l) {
      rmsnorm_k<<<dim3(B), dim3(256), 0, stream>>>(h, w_in_norm + (size_t)l * H, x);
      // v = x @ wv  [256,1024]x[1024,512]
      gemm_k<32, 32, 32, 2, 2, false, false, false>
          <<<dim3(KV / 32, B / 32), dim3(256), 0, stream>>>(
              x, H, w_v + (size_t)l * H * KV, v, B, KV, H);
      // h += gather(v) @ wo  [256,1024(logical)]x[1024,1024]
      gemm_k<32, 32, 32, 2, 2, true, true, false>
          <<<dim3(H / 32, B / 32), dim3(256), 0, stream>>>(
              v, KV, w_o + (size_t)l * H * H, h, B, H, H);
      rmsnorm_k<<<dim3(B), dim3(256), 0, stream>>>(h, w_post + (size_t)l * H, x);
      // m = silu(x@wg)*(x@wu)  [256,1024]x[1024,4096]
      gemm_gu_k<64, 64, 32, 4, 4>
          <<<dim3(I / 64, B / 64), dim3(256), 0, stream>>>(
              x, w_gate + (size_t)l * H * I, w_up + (size_t)l * H * I, m, B, I, H);
      // h += m @ wd  [256,4096]x[4096,1024]
      gemm_k<32, 32, 32, 2, 2, false, true, false>
          <<<dim3(H / 32, B / 32), dim3(256), 0, stream>>>(
              m, I, w_down + (size_t)l * I * H, h, B, H, I);
    }
    rmsnorm_k<<<dim3(B), dim3(256), 0, stream>>>(h, fnorm, x);
    // logits = x @ lm_heads[i]^T  (B transposed: [1027,1024])
    gemm_k<32, 32, 32, 2, 2, false, false, true>
        <<<dim3((V + 31) / 32, B / 32), dim3(256), 0, stream>>>(
            x, H, lm + (size_t)i * V * H, logits, B, V, H);
    reppen_k<<<dim3(1), dim3(256), 0, stream>>>(logits, gh, gen_step, i);
    sample_k<<<dim3(B), dim3(256), 0, stream>>>(logits, i, toks, out);
    if (i < C - 1)
      embed_k<<<dim3(B), dim3(256), 0, stream>>>(h, embed + (size_t)(i + 1) * V * H, toks);
  }
}

// Round 2
// 11287.201 us; speedup vs baseline: 4.7351x; 4.7351x over previous
//
#include <hip/hip_runtime.h>
#include <cstdint>
#include <cfloat>
#include <cmath>

// ---------------------------------------------------------------------------
// MossTTS local transformer decode. B=256,H=1024,L=4,HKV=8,D=64,I=4096,V=1027,C=16.
// seq_len==1 -> attention == repeat(v); w_q/w_k/q_norm/k_norm dead.
// This round: fp32 GEMMs rebuilt for occupancy: 64x64x32 tiles, 4x4/thread,
// deterministic split-K (fixed-order reduce, no float atomics), Wo folded to
// K=512 (gather removed), rmsnorm fused into GEMM A-staging via per-row r[b],
// logits-reduce+reppen+sample+embed+rms fused into one head kernel.
// Runtime ws_size switch: big path (~22.6MB) vs proven-safe small path (7.87MB).
// ---------------------------------------------------------------------------

#define PARTITIONABLE 1

namespace {
constexpr int B = 256, H = 1024, L = 4;
constexpr int I = 4096, V = 1027, C = 16;
constexpr int KV = 512;
}

// ------------------------------ threefry2x32 -------------------------------
__device__ __forceinline__ void tf2x32(uint32_t k0, uint32_t k1,
                                       uint32_t x0, uint32_t x1,
                                       uint32_t& o0, uint32_t& o1) {
  uint32_t k2 = k0 ^ k1 ^ 0x1BD11BDAu;
  x0 += k0; x1 += k1;
#define TFR(r) { x0 += x1; x1 = (x1 << r) | (x1 >> (32 - r)); x1 ^= x0; }
  TFR(13) TFR(15) TFR(26) TFR(6)
  x0 += k1; x1 += k2 + 1u;
  TFR(17) TFR(29) TFR(16) TFR(24)
  x0 += k2; x1 += k0 + 2u;
  TFR(13) TFR(15) TFR(26) TFR(6)
  x0 += k0; x1 += k1 + 3u;
  TFR(17) TFR(29) TFR(16) TFR(24)
  x0 += k1; x1 += k2 + 4u;
  TFR(13) TFR(15) TFR(26) TFR(6)
  x0 += k2; x1 += k0 + 5u;
#undef TFR
  o0 = x0; o1 = x1;
}

__device__ __forceinline__ float gumbel_for(uint32_t k0, uint32_t k1,
                                            uint32_t idx) {
  uint32_t o0, o1, bits;
  tf2x32(k0, k1, 0u, idx, o0, o1);
  bits = o0 ^ o1;
  float f = __uint_as_float((bits >> 9) | 0x3f800000u) - 1.0f;
  float u = fmaxf(FLT_MIN, f + FLT_MIN);
  return -logf(-logf(u));
}

// --------------------------- small fused kernels ---------------------------
// h = backbone ; r[b] = rsqrt(mean(h^2)+eps). Block per row.
__global__ __launch_bounds__(256) void copy_rms_k(const float* __restrict__ src,
                                                  float* __restrict__ h,
                                                  float* __restrict__ r) {
  int b = blockIdx.x, tid = threadIdx.x;
  float4 v = *(const float4*)&src[(size_t)b * H + tid * 4];
  *(float4*)&h[(size_t)b * H + tid * 4] = v;
  float s = v.x * v.x + v.y * v.y + v.z * v.z + v.w * v.w;
  for (int off = 32; off > 0; off >>= 1) s += __shfl_down(s, off, 64);
  __shared__ float red[4];
  if ((tid & 63) == 0) red[tid >> 6] = s;
  __syncthreads();
  if (tid == 0) {
    float t = red[0] + red[1] + red[2] + red[3];
    r[b] = 1.0f / sqrtf(t * (1.0f / 1024.0f) + 1e-6f);
  }
}

// Wo' [L][512][1024]: fold the repeat-KV gather: Wo'[c,n] = Wo[kb*128+j,n] + Wo[kb*128+j+64,n]
__global__ __launch_bounds__(256) void fold_k(const float* __restrict__ wo,
                                              float* __restrict__ wof) {
  int blk = blockIdx.x;             // l*512 + c
  int l = blk >> 9, c = blk & 511;
  int kb = c >> 6, jl = c & 63;
  const float* w = wo + (size_t)l * H * H;
  int k1 = kb * 128 + jl, k2 = k1 + 64;
  int j = threadIdx.x * 4;
  float4 a = *(const float4*)&w[(size_t)k1 * H + j];
  float4 bq = *(const float4*)&w[(size_t)k2 * H + j];
  float4 o = {a.x + bq.x, a.y + bq.y, a.z + bq.z, a.w + bq.w};
  *(float4*)&wof[((size_t)l * KV + c) * H + j] = o;
}

// ------------------------------ GEMM 64x64x32 ------------------------------
// Split-K partial GEMM. A is [256, lda]; if NORM, A_logical = h*r[row]*wn[k].
// If GATHER, A column = ((k>>7)<<6)|(k&63) (repeat-KV). B normal [K,N] or
// BT [N,K]. Writes partial C for split blockIdx.z at Cp + z*256*N.
template <bool NORM, bool GATHER, bool BT, bool BOUND>
__global__ __launch_bounds__(256) void gemm64_k(
    const float* __restrict__ A, int lda,
    const float* __restrict__ rv, const float* __restrict__ wn,
    const float* __restrict__ Bm, int ldb,
    float* __restrict__ Cp, int N, int Kslice) {
  __shared__ __align__(16) float As[32][68];
  __shared__ __align__(16) float Bs[32][68];
  const int tid = threadIdx.x;
  const int tx = tid & 15, ty = tid >> 4;
  const int bm = blockIdx.y * 64;
  const int bn = blockIdx.x * 64;
  const int ks0 = blockIdx.z * Kslice;
  float4 acc[4];
#pragma unroll
  for (int i = 0; i < 4; ++i) acc[i] = float4{0.f, 0.f, 0.f, 0.f};

  for (int k0 = 0; k0 < Kslice; k0 += 32) {
    const int kbase = ks0 + k0;
#pragma unroll
    for (int s = 0; s < 2; ++s) {
      int slot = tid + s * 256;
      int rI = slot >> 3, c = slot & 7;
      int k = kbase + c * 4;
      int col = GATHER ? (((k >> 7) << 6) | (k & 63)) : k;
      float4 av = *(const float4*)&A[(size_t)(bm + rI) * lda + col];
      if (NORM) {
        float sc = rv[bm + rI];
        float4 wv = *(const float4*)&wn[k];
        av.x *= sc * wv.x; av.y *= sc * wv.y;
        av.z *= sc * wv.z; av.w *= sc * wv.w;
      }
      As[c * 4 + 0][rI] = av.x; As[c * 4 + 1][rI] = av.y;
      As[c * 4 + 2][rI] = av.z; As[c * 4 + 3][rI] = av.w;
    }
#pragma unroll
    for (int s = 0; s < 2; ++s) {
      int slot = tid + s * 256;
      if (!BT) {
        int kI = slot >> 4, c4 = slot & 15;
        float4 bv = *(const float4*)&Bm[(size_t)(kbase + kI) * ldb + bn + c4 * 4];
        *(float4*)&Bs[kI][c4 * 4] = bv;
      } else {
        int nI = slot >> 3, c = slot & 7;
        int n = bn + nI;
        float4 bv = {0.f, 0.f, 0.f, 0.f};
        if (!BOUND || n < N)
          bv = *(const float4*)&Bm[(size_t)n * ldb + kbase + c * 4];
        Bs[c * 4 + 0][nI] = bv.x; Bs[c * 4 + 1][nI] = bv.y;
        Bs[c * 4 + 2][nI] = bv.z; Bs[c * 4 + 3][nI] = bv.w;
      }
    }
    __syncthreads();
#pragma unroll
    for (int kk = 0; kk < 32; ++kk) {
      float4 a = *(const float4*)&As[kk][ty * 4];
      float4 b = *(const float4*)&Bs[kk][tx * 4];
      float ar[4] = {a.x, a.y, a.z, a.w};
#pragma unroll
      for (int i = 0; i < 4; ++i) {
        acc[i].x = fmaf(ar[i], b.x, acc[i].x);
        acc[i].y = fmaf(ar[i], b.y, acc[i].y);
        acc[i].z = fmaf(ar[i], b.z, acc[i].z);
        acc[i].w = fmaf(ar[i], b.w, acc[i].w);
      }
    }
    __syncthreads();
  }
  float* base = Cp + (size_t)blockIdx.z * 256 * N;
#pragma unroll
  for (int i = 0; i < 4; ++i) {
    int row = bm + ty * 4 + i;
    int colb = bn + tx * 4;
    if (!BOUND) {
      *(float4*)&base[(size_t)row * N + colb] = acc[i];
    } else {
      float vals[4] = {acc[i].x, acc[i].y, acc[i].z, acc[i].w};
      for (int j = 0; j < 4; ++j)
        if (colb + j < N) base[(size_t)row * N + colb + j] = vals[j];
    }
  }
}

// -------------------- fused gate/up GEMM, 64x32x32, silu --------------------
// m = silu(x@Wg) * (x@Wu); x = h*r*wn fused in staging. Full K, no split.
__global__ __launch_bounds__(256) void gemm_gu_k(
    const float* __restrict__ hm, const float* __restrict__ rv,
    const float* __restrict__ wn,
    const float* __restrict__ Bg, const float* __restrict__ Bu,
    float* __restrict__ Mo) {
  __shared__ __align__(16) float As[32][68];
  __shared__ __align__(16) float Gs[32][36];
  __shared__ __align__(16) float Us[32][36];
  const int tid = threadIdx.x;
  const int tx = tid & 15, ty = tid >> 4;
  const int bm = blockIdx.y * 64;
  const int bn = blockIdx.x * 32;
  float2 ag[4], au[4];
#pragma unroll
  for (int i = 0; i < 4; ++i) { ag[i] = float2{0.f, 0.f}; au[i] = float2{0.f, 0.f}; }

  for (int k0 = 0; k0 < H; k0 += 32) {
#pragma unroll
    for (int s = 0; s < 2; ++s) {
      int slot = tid + s * 256;
      int rI = slot >> 3, c = slot & 7;
      int k = k0 + c * 4;
      float4 av = *(const float4*)&hm[(size_t)(bm + rI) * H + k];
      float sc = rv[bm + rI];
      float4 wv = *(const float4*)&wn[k];
      av.x *= sc * wv.x; av.y *= sc * wv.y;
      av.z *= sc * wv.z; av.w *= sc * wv.w;
      As[c * 4 + 0][rI] = av.x; As[c * 4 + 1][rI] = av.y;
      As[c * 4 + 2][rI] = av.z; As[c * 4 + 3][rI] = av.w;
    }
    {
      int kI = tid >> 3, c4 = tid & 7;
      float4 gv = *(const float4*)&Bg[(size_t)(k0 + kI) * I + bn + c4 * 4];
      float4 uv = *(const float4*)&Bu[(size_t)(k0 + kI) * I + bn + c4 * 4];
      *(float4*)&Gs[kI][c4 * 4] = gv;
      *(float4*)&Us[kI][c4 * 4] = uv;
    }
    __syncthreads();
#pragma unroll
    for (int kk = 0; kk < 32; ++kk) {
      float4 a = *(const float4*)&As[kk][ty * 4];
      float2 g = *(const float2*)&Gs[kk][tx * 2];
      float2 u = *(const float2*)&Us[kk][tx * 2];
      float ar[4] = {a.x, a.y, a.z, a.w};
#pragma unroll
      for (int i = 0; i < 4; ++i) {
        ag[i].x = fmaf(ar[i], g.x, ag[i].x);
        ag[i].y = fmaf(ar[i], g.y, ag[i].y);
        au[i].x = fmaf(ar[i], u.x, au[i].x);
        au[i].y = fmaf(ar[i], u.y, au[i].y);
      }
    }
    __syncthreads();
  }
#pragma unroll
  for (int i = 0; i < 4; ++i) {
    int row = bm + ty * 4 + i;
    int col = bn + tx * 2;
    float g0 = ag[i].x, g1 = ag[i].y;
    float s0 = 1.0f / (1.0f + expf(-g0));
    float s1 = 1.0f / (1.0f + expf(-g1));
    float2 o = {g0 * s0 * au[i].x, g1 * s1 * au[i].y};
    *(float2*)&Mo[(size_t)row * I + col] = o;
  }
}

// ------------------------------ reductions ---------------------------------
__global__ __launch_bounds__(256) void red_v_k(const float* __restrict__ part,
                                               float* __restrict__ v, int S) {
  int i4 = (blockIdx.x * 256 + threadIdx.x) * 4;
  float4 s = {0.f, 0.f, 0.f, 0.f};
  for (int ss = 0; ss < S; ++ss) {
    float4 p = *(const float4*)&part[(size_t)ss * (256 * KV) + i4];
    s.x += p.x; s.y += p.y; s.z += p.z; s.w += p.w;
  }
  *(float4*)&v[i4] = s;
}

// h += sum(partials) ; r[b] = rsqrt(mean(h^2)+eps). Block per row, N=1024.
__global__ __launch_bounds__(256) void red_add_rms_k(const float* __restrict__ part,
                                                     float* __restrict__ h,
                                                     float* __restrict__ r, int S) {
  int b = blockIdx.x, tid = threadIdx.x;
  size_t off = (size_t)b * H + tid * 4;
  float4 a = *(const float4*)&h[off];
  for (int ss = 0; ss < S; ++ss) {
    float4 p = *(const float4*)&part[(size_t)ss * (256 * H) + off];
    a.x += p.x; a.y += p.y; a.z += p.z; a.w += p.w;
  }
  *(float4*)&h[off] = a;
  float s = a.x * a.x + a.y * a.y + a.z * a.z + a.w * a.w;
  for (int o = 32; o > 0; o >>= 1) s += __shfl_down(s, o, 64);
  __shared__ float red[4];
  if ((tid & 63) == 0) red[tid >> 6] = s;
  __syncthreads();
  if (tid == 0) {
    float t = red[0] + red[1] + red[2] + red[3];
    r[b] = 1.0f / sqrtf(t * (1.0f / 1024.0f) + 1e-6f);
  }
}

// --------------------------- head: reduce+reppen+sample+embed --------------
__global__ __launch_bounds__(256) void head_k(
    const float* __restrict__ part, int S,
    const int* __restrict__ gh, const int* __restrict__ gen_step_p,
    int step, const float* __restrict__ embed_next,
    float* __restrict__ h, float* __restrict__ r,
    int* __restrict__ out) {
  constexpr int TOPK = 30;
  constexpr int KMAX = 64;
  const int b = blockIdx.x, tid = threadIdx.x;
  __shared__ float sl[V];
  __shared__ float rv_[256]; __shared__ int ri[256];
  __shared__ float topv[TOPK]; __shared__ int topi[TOPK];
  __shared__ float kv[KMAX]; __shared__ int ki[KMAX]; __shared__ int keepf[KMAX];
  __shared__ uint32_t skey[2];
  __shared__ int scnt, sn, stok;
  __shared__ float redf[4];

  if (tid == 0) {
    uint32_t o0, o1;
    tf2x32(0u, 1234u, 0u, (uint32_t)step, o0, o1);
    skey[0] = o0; skey[1] = o1;
    scnt = 0;
  }
  // sum split-K partials of the logits row
  for (int v = tid; v < V; v += 256) {
    float s = 0.f;
    for (int ss = 0; ss < S; ++ss)
      s += part[(size_t)ss * (256 * V) + (size_t)b * V + v];
    sl[v] = s;
  }
  __syncthreads();
  // repetition penalty (read-all-then-write .set semantics; dup writes identical)
  int gs = *gen_step_p;
  int cnt = gs < 50 ? gs : 50;
  int start = gs - cnt;
  int tkn = -1; float val = 0.f;
  if (tid < cnt) {
    tkn = gh[(size_t)b * 200 * C + (size_t)(start + tid) * C + step];
    val = sl[tkn];
  }
  __syncthreads();
  if (tid < cnt) sl[tkn] = (val < 0.f) ? val * 1.1f : val / 1.1f;
  __syncthreads();
  for (int v = tid; v < V; v += 256) sl[v] = sl[v] / 0.8f;
  __syncthreads();

  // iterative top-30 (argmax, lowest-index tiebreak)
  for (int it = 0; it < TOPK; ++it) {
    float bv = -INFINITY; int bi = 0x7fffffff;
    for (int v = tid; v < V; v += 256) {
      float x = sl[v];
      if (x > bv) { bv = x; bi = v; }
    }
    rv_[tid] = bv; ri[tid] = bi;
    __syncthreads();
    for (int s = 128; s > 0; s >>= 1) {
      if (tid < s) {
        float ov = rv_[tid + s]; int oi = ri[tid + s];
        if (ov > rv_[tid] || (ov == rv_[tid] && oi < ri[tid])) { rv_[tid] = ov; ri[tid] = oi; }
      }
      __syncthreads();
    }
    if (tid == 0) { topv[it] = rv_[0]; topi[it] = ri[0]; sl[ri[0]] = -INFINITY; }
    __syncthreads();
  }
  if (tid < TOPK) sl[topi[tid]] = topv[tid];
  __syncthreads();
  const float thr = topv[TOPK - 1];
  for (int v = tid; v < V; v += 256) {
    if (sl[v] >= thr) {
      int p = atomicAdd(&scnt, 1);
      if (p < KMAX) { kv[p] = sl[v]; ki[p] = v; }
    }
  }
  __syncthreads();

  if (tid == 0) {
    int n = scnt < KMAX ? scnt : KMAX;
    for (int a = 1; a < n; ++a) {  // stable ascending (value,index) sort
      float cv = kv[a]; int ci = ki[a];
      int p = a - 1;
      while (p >= 0 && (kv[p] > cv || (kv[p] == cv && ki[p] > ci))) {
        kv[p + 1] = kv[p]; ki[p + 1] = ki[p]; --p;
      }
      kv[p + 1] = cv; ki[p + 1] = ci;
    }
    float mx = kv[n - 1];
    float denom = 0.f;
    for (int j = 0; j < n; ++j) denom += expf(kv[j] - mx);
    float c = 0.f;
    for (int j = 0; j < n; ++j) {
      float p = expf(kv[j] - mx) / denom;
      c += p;
      keepf[j] = ((double)c > 0.4) ? 1 : 0;
    }
    sn = n;
  }
  __syncthreads();

  int n = sn;
  rv_[tid] = -INFINITY; ri[tid] = 0x7fffffff;
  if (tid < n && keepf[tid]) {
    uint32_t idx = (uint32_t)b * (uint32_t)V + (uint32_t)ki[tid];
    float g = gumbel_for(skey[0], skey[1], idx);
    rv_[tid] = kv[tid] + g;
    ri[tid] = ki[tid];
  }
  __syncthreads();
  for (int s = 128; s > 0; s >>= 1) {
    if (tid < s) {
      float ov = rv_[tid + s]; int oi = ri[tid + s];
      if (ov > rv_[tid] || (ov == rv_[tid] && oi < ri[tid])) { rv_[tid] = ov; ri[tid] = oi; }
    }
    __syncthreads();
  }
  if (tid == 0) {
    stok = ri[0];
    out[(size_t)b * C + step] = ri[0];
  }
  __syncthreads();

  // next-step embedding + rms scale, fused
  if (embed_next != nullptr) {
    int tok = stok;
    float4 e = *(const float4*)&embed_next[(size_t)tok * H + tid * 4];
    *(float4*)&h[(size_t)b * H + tid * 4] = e;
    float s = e.x * e.x + e.y * e.y + e.z * e.z + e.w * e.w;
    for (int o = 32; o > 0; o >>= 1) s += __shfl_down(s, o, 64);
    if ((tid & 63) == 0) redf[tid >> 6] = s;
    __syncthreads();
    if (tid == 0) {
      float t = redf[0] + redf[1] + redf[2] + redf[3];
      r[b] = 1.0f / sqrtf(t * (1.0f / 1024.0f) + 1e-6f);
    }
  }
}

// ------------------------------ launch -------------------------------------
extern "C" void kernel_launch(void* const* d_in, const int* in_sizes, int n_in,
                              void* d_out, int out_size, void* d_ws, size_t ws_size,
                              hipStream_t stream) {
  const float* backbone = (const float*)d_in[0];
  const int*   gh       = (const int*)d_in[1];
  const int*   gen_step = (const int*)d_in[2];
  const float* embed    = (const float*)d_in[3];
  const float* lm       = (const float*)d_in[4];
  const float* w_in     = (const float*)d_in[5];
  // d_in[6]=w_q, d_in[7]=w_k, d_in[9]=q_norm, d_in[10]=k_norm dead (seq_len==1)
  const float* w_v      = (const float*)d_in[8];
  const float* w_o      = (const float*)d_in[11];
  const float* w_post   = (const float*)d_in[12];
  const float* w_g      = (const float*)d_in[13];
  const float* w_u      = (const float*)d_in[14];
  const float* w_d      = (const float*)d_in[15];
  const float* fnorm    = (const float*)d_in[16];
  int* out = (int*)d_out;
  float* ws = (float*)d_ws;

  // big path needs 5,642,752 floats (~22.6MB); small path fits proven 7.87MB
  const bool big = ws_size >= (size_t)22600000;
  float* h    = ws;                                   // 262144
  float* v    = ws + 262144;                          // 131072
  float* m    = ws + 393216;                          // 1048576
  float* wof  = big ? ws + 1441792 : nullptr;         // 2097152 (big only)
  float* part = big ? ws + 3538944 : ws + 1441792;    // 2103296 / 524288
  float* r    = big ? ws + 5642240 : ws + 1966080;    // 256

  const int S1 = big ? 16 : 4;
  const int S2 = big ? 8 : 2;
  const int S4 = big ? 8 : 2;
  const int S5 = big ? 8 : 1;

  copy_rms_k<<<dim3(256), dim3(256), 0, stream>>>(backbone, h, r);
  if (big) fold_k<<<dim3(2048), dim3(256), 0, stream>>>(w_o, wof);

  for (int i = 0; i < C; ++i) {
    for (int l = 0; l < L; ++l) {
      // v = rms(h)*wi @ Wv   [256,1024]x[1024,512], split-K
      gemm64_k<true, false, false, false><<<dim3(8, 4, S1), dim3(256), 0, stream>>>(
          h, H, r, w_in + (size_t)l * H, w_v + (size_t)l * H * KV, KV,
          part, KV, H / S1);
      red_v_k<<<dim3(128), dim3(256), 0, stream>>>(part, v, S1);
      // h += v @ Wo' (folded, K=512) or gather path (small)
      if (big)
        gemm64_k<false, false, false, false><<<dim3(16, 4, S2), dim3(256), 0, stream>>>(
            v, KV, nullptr, nullptr, wof + (size_t)l * KV * H, H,
            part, H, KV / S2);
      else
        gemm64_k<false, true, false, false><<<dim3(16, 4, S2), dim3(256), 0, stream>>>(
            v, KV, nullptr, nullptr, w_o + (size_t)l * H * H, H,
            part, H, H / S2);
      red_add_rms_k<<<dim3(256), dim3(256), 0, stream>>>(part, h, r, S2);
      // m = silu(x2@Wg)*(x2@Wu), x2 = rms(h)*wp fused; no split, silu fused
      gemm_gu_k<<<dim3(128, 4), dim3(256), 0, stream>>>(
          h, r, w_post + (size_t)l * H,
          w_g + (size_t)l * H * I, w_u + (size_t)l * H * I, m);
      // h += m @ Wd   [256,4096]x[4096,1024], split-K
      gemm64_k<false, false, false, false><<<dim3(16, 4, S4), dim3(256), 0, stream>>>(
          m, I, nullptr, nullptr, w_d + (size_t)l * I * H, H,
          part, H, I / S4);
      red_add_rms_k<<<dim3(256), dim3(256), 0, stream>>>(part, h, r, S4);
    }
    // logits partials = rms(h)*fnorm @ lm[i]^T  (BT, N=1027 bounds)
    gemm64_k<true, false, true, true><<<dim3(17, 4, S5), dim3(256), 0, stream>>>(
        h, H, r, fnorm, lm + (size_t)i * V * H, H, part, V, H / S5);
    head_k<<<dim3(256), dim3(256), 0, stream>>>(
        part, S5, gh, gen_step, i,
        (i < C - 1) ? embed + (size_t)(i + 1) * V * H : nullptr,
        h, r, out);
  }
}